// Round 6
// baseline (419.526 us; speedup 1.0000x reference)
//
#include <hip/hip_runtime.h>
#include <cstdint>
#include <cstddef>

#define N_PTS 50000
#define H 16
#define CIN 256
#define C 256
#define CPG 32
#define CR 64

typedef short bf16x8 __attribute__((ext_vector_type(8)));
typedef float f32x4 __attribute__((ext_vector_type(4)));

__device__ __forceinline__ unsigned short f2bf(float f) {
    unsigned int u = __float_as_uint(f);
    u += 0x7fff + ((u >> 16) & 1);
    return (unsigned short)(u >> 16);
}
__device__ __forceinline__ float bf2f(unsigned short s) {
    return __uint_as_float(((unsigned int)s) << 16);
}

// ---------------------------------------------------------------------------
// Merged prep: [0,6250) convert s_feats->bf16; [6250,6346) pack Wq|Wk|Wv
// B-frags; [6346,6359) pack Wd2/Wa1/Wa2 B-frags.
//   frag(kt,nt): lane l holds B[kt*32+(l>>4)*8+j][nt*16+(l&15)], j=0..7
// ---------------------------------------------------------------------------
__global__ __launch_bounds__(256) void prep_all(
    const float* __restrict__ feats,
    const float* __restrict__ Wq, const float* __restrict__ Wk,
    const float* __restrict__ Wv,
    const float* __restrict__ Wd2, const float* __restrict__ Wa1,
    const float* __restrict__ Wa2,
    unsigned short* __restrict__ A_bf16,
    unsigned short* __restrict__ gemmFrags,
    unsigned short* __restrict__ attnFrags)
{
    int bid = blockIdx.x;
    if (bid < 6250) {
        size_t i = ((size_t)bid * 256 + threadIdx.x) * 8;
        float4 f0 = *(const float4*)&feats[i];
        float4 f1 = *(const float4*)&feats[i + 4];
        unsigned short t[8] = {f2bf(f0.x), f2bf(f0.y), f2bf(f0.z), f2bf(f0.w),
                               f2bf(f1.x), f2bf(f1.y), f2bf(f1.z), f2bf(f1.w)};
        *(bf16x8*)&A_bf16[i] = *(bf16x8*)t;
    } else if (bid < 6346) {
        int t = (bid - 6250) * 256 + threadIdx.x;   // 0..24575
        int lane = t & 63;
        int f = t >> 6;                              // kt*48 + ntg
        int ntg = f % 48;
        const float* W = ntg < 16 ? Wq : (ntg < 32 ? Wk : Wv);
        int colc = (ntg & 15) * 16 + (lane & 15);
        int row0 = (f / 48) * 32 + ((lane >> 4) << 3);
        unsigned short tmp[8];
        #pragma unroll
        for (int j = 0; j < 8; ++j) tmp[j] = f2bf(W[(size_t)(row0 + j) * 256 + colc]);
        *(bf16x8*)&gemmFrags[(size_t)t * 8] = *(bf16x8*)tmp;
    } else {
        int t = (bid - 6346) * 256 + threadIdx.x;
        if (t >= 3200) return;
        const float* W; int Nc, NT, loc, base;
        if (t < 2048)      { W = Wd2; Nc = 256; NT = 16; loc = t;        base = 0; }
        else if (t < 3072) { W = Wa1; Nc = 32;  NT = 2;  loc = t - 2048; base = 16384; }
        else               { W = Wa2; Nc = 32;  NT = 2;  loc = t - 3072; base = 24576; }
        int f = loc >> 6, lane = loc & 63;
        int kt = f / NT, nt = f - kt * NT;
        int colc = nt * 16 + (lane & 15);
        int row0 = kt * 32 + ((lane >> 4) << 3);
        unsigned short tmp[8];
        #pragma unroll
        for (int j = 0; j < 8; ++j) tmp[j] = f2bf(W[(size_t)(row0 + j) * Nc + colc]);
        *(bf16x8*)&attnFrags[(size_t)(base + loc * 8)] = *(bf16x8*)tmp;
    }
}

// ---------------------------------------------------------------------------
// QKV GEMM v2 (unchanged): barrier-free, LDS-free.
// kv interleaved output: row = [0..255]=q, [256+2c]=k[c], [257+2c]=v[c].
// ---------------------------------------------------------------------------
__global__ __launch_bounds__(256) void qkv_gemm_mfma(
    const unsigned short* __restrict__ A,       // [N][256] bf16
    const unsigned short* __restrict__ wfrags,
    const float* __restrict__ bq, const float* __restrict__ bk,
    const float* __restrict__ bv, unsigned short* __restrict__ out)
{
    const int tid = threadIdx.x;
    const int lane = tid & 63, wave = tid >> 6;
    const int quad = lane >> 4, col16 = lane & 15;
    const int bx = blockIdx.x, by = blockIdx.y;

    int r0 = by * 128 + wave * 32 + col16;
    int r1 = r0 + 16;
    r0 = r0 < N_PTS ? r0 : N_PTS - 1;
    r1 = r1 < N_PTS ? r1 : N_PTS - 1;
    const unsigned short* a0p = &A[(size_t)r0 * 256 + quad * 8];
    const unsigned short* a1p = &A[(size_t)r1 * 256 + quad * 8];
    const unsigned short* bp  = &wfrags[(((size_t)bx * 8) * 64 + lane) * 8];

    f32x4 acc[2][8] = {};

    #pragma unroll 2
    for (int kt = 0; kt < 8; ++kt) {
        bf16x8 af0 = *(const bf16x8*)(a0p + kt * 32);
        bf16x8 af1 = *(const bf16x8*)(a1p + kt * 32);
        const unsigned short* bkt = bp + (size_t)kt * 48 * 64 * 8;
        #pragma unroll
        for (int nt = 0; nt < 8; ++nt) {
            bf16x8 bf = *(const bf16x8*)(bkt + (size_t)nt * 64 * 8);
            acc[0][nt] = __builtin_amdgcn_mfma_f32_16x16x32_bf16(af0, bf, acc[0][nt], 0, 0, 0);
            acc[1][nt] = __builtin_amdgcn_mfma_f32_16x16x32_bf16(af1, bf, acc[1][nt], 0, 0, 0);
        }
    }

    const int mode = bx >> 1;   // 0=q 1=k 2=v
    const float* bias = mode == 0 ? bq : (mode == 1 ? bk : bv);
    #pragma unroll
    for (int nt = 0; nt < 8; ++nt) {
        int cIn = (bx & 1) * 128 + nt * 16 + col16;
        float bb = bias[cIn];
        int pos = mode == 0 ? cIn : (256 + 2 * cIn + (mode == 2 ? 1 : 0));
        #pragma unroll
        for (int mt = 0; mt < 2; ++mt) {
            #pragma unroll
            for (int r = 0; r < 4; ++r) {
                int row = by * 128 + wave * 32 + mt * 16 + quad * 4 + r;
                if (row < N_PTS)
                    out[(size_t)row * 768 + pos] = f2bf(acc[mt][nt][r] + bb);
            }
        }
    }
}

// ---------------------------------------------------------------------------
// Fused attention v7: PAIR processing, 8 points/block.
// Round 2-5 evidence: gather-prefetch regressed (r4), occupancy stuck at 3
// blocks/CU regardless of hints (r4/r5). Remaining wait time is barrier +
// idle-wave serialization: v3 ran a1/a2 on waves 0-1 only and softmax on
// wave 0 only, with 5 barriers per point.
// v7: two points advance through the MLP together -- waves 0-1 run p0's
// a1/a2 (buffer pw=0), waves 2-3 run p1's (pw=1); softmax wave0->p0,
// wave1->p1. 5 barriers per TWO points (halved), MLP at full block width.
// 8 points/block amortizes the weight-frag prologue. Plain __syncthreads.
// LDS 47.2KB -> still 3 blocks/CU (the cap we're pinned at anyway).
// ---------------------------------------------------------------------------
#define D1S 72
#define PGS 66      // private geom row stride (dwords): 2-way banks on rd & wr
#define QKS 264
#define A1S 40
#define A2S 33
#define PPB 8       // points per block

__global__ __launch_bounds__(256) void attn_mfma(
    const unsigned short* __restrict__ qkv,     // [N][768] q | kv-interleaved
    const float* __restrict__ q_pts, const float* __restrict__ s_pts,
    const int* __restrict__ nbr,
    const float* __restrict__ Wd1, const float* __restrict__ bd1,
    const float* __restrict__ bd2,
    const unsigned short* __restrict__ frags,
    const float* __restrict__ ba1, const float* __restrict__ ba2,
    float* __restrict__ out)
{
    __shared__ unsigned short s_d1[2][H * D1S];
    __shared__ float          s_pg[4 * H * PGS];   // wave-private geom tiles
    __shared__ unsigned short s_qk[2][H * QKS];
    __shared__ unsigned short s_a1[2][H * A1S];
    __shared__ float          s_a2[2][H * A2S];
    __shared__ float          s_rel[PPB][H][3];
    __shared__ int            s_idx[PPB][H];

    const int tid = threadIdx.x;
    const int lane = tid & 63, wave = tid >> 6;
    const int quad = lane >> 4, col = lane & 15;
    const int pw = wave >> 1;          // which point of the pair (MLP stages)
    const int hx = wave & 1;           // which 16-col half of CPG=32
    const int n0 = blockIdx.x * PPB;
    const int c = tid;                 // == wave*64 + lane

    if (tid < PPB * H) {
        int pp = tid >> 4, hh = tid & 15;
        int idx = nbr[(size_t)(n0 + pp) * H + hh];
        s_idx[pp][hh] = idx;
        #pragma unroll
        for (int x = 0; x < 3; ++x)
            s_rel[pp][hh][x] = s_pts[(size_t)idx * 3 + x] - q_pts[(size_t)(n0 + pp) * 3 + x];
    }

    const float w1x = Wd1[lane], w1y = Wd1[64 + lane], w1z = Wd1[128 + lane];
    const float b1 = bd1[lane];
    const float b2 = bd2[c];
    bf16x8 wd2f[2][4];
    #pragma unroll
    for (int t = 0; t < 4; ++t) {
        wd2f[0][t] = *(const bf16x8*)&frags[((size_t)((0 * 16 + wave * 4 + t) * 64 + lane)) * 8];
        wd2f[1][t] = *(const bf16x8*)&frags[((size_t)((1 * 16 + wave * 4 + t) * 64 + lane)) * 8];
    }
    // ALL waves load the attn-MLP frags now (indexed by column-half hx)
    bf16x8 wa1f[8];
    #pragma unroll
    for (int kt = 0; kt < 8; ++kt)
        wa1f[kt] = *(const bf16x8*)&frags[16384 + ((size_t)((kt * 2 + hx) * 64 + lane)) * 8];
    bf16x8 wa2f = *(const bf16x8*)&frags[24576 + ((size_t)(hx * 64 + lane)) * 8];
    __syncthreads();

    float* pg = &s_pg[wave * (H * PGS)];

    for (int pr = 0; pr < PPB / 2; ++pr) {
        const int p0 = 2 * pr, p1 = 2 * pr + 1;

        // ---- d1 = lrelu(rel @ Wd1 + bd1) for BOTH points of the pair
        #pragma unroll
        for (int pt = 0; pt < 2; ++pt) {
            #pragma unroll
            for (int pass = 0; pass < 4; ++pass) {
                int h = pass * 4 + wave;
                const float* rel = s_rel[p0 + pt][h];
                float v = b1 + rel[0] * w1x + rel[1] * w1y + rel[2] * w1z;
                s_d1[pt][h * D1S + lane] = f2bf(fmaxf(v, 0.1f * v));
            }
        }
        __syncthreads();                                    // bar 1

        float vg0[H], vg1[H];

        // ---- front stage, point 0: gathers -> geom -> vg/qk build
        {
            unsigned int u[H];
            #pragma unroll
            for (int h = 0; h < H; ++h)
                u[h] = *(const unsigned int*)&qkv[(size_t)s_idx[p0][h] * 768 + 256 + 2 * c];
            float qf = bf2f(qkv[(size_t)s_idx[p0][0] * 768 + c]);

            bf16x8 ga = *(bf16x8*)&s_d1[0][col * D1S + quad * 8];
            bf16x8 gb = *(bf16x8*)&s_d1[0][col * D1S + 32 + quad * 8];
            #pragma unroll
            for (int t = 0; t < 4; ++t) {
                f32x4 acc = {0.f, 0.f, 0.f, 0.f};
                acc = __builtin_amdgcn_mfma_f32_16x16x32_bf16(ga, wd2f[0][t], acc, 0, 0, 0);
                acc = __builtin_amdgcn_mfma_f32_16x16x32_bf16(gb, wd2f[1][t], acc, 0, 0, 0);
                #pragma unroll
                for (int rr = 0; rr < 4; ++rr)
                    pg[(quad * 4 + rr) * PGS + t * 16 + col] = acc[rr];
            }
            // same-wave ds_write->ds_read: lgkmcnt ordering, no barrier.
            #pragma unroll
            for (int h = 0; h < H; ++h) {
                float g = pg[h * PGS + lane] + b2;
                float nk = __uint_as_float(u[h] << 16);
                float nv = __uint_as_float(u[h] & 0xffff0000u);
                vg0[h] = nv - g;
                float tq = qf - nk - g;
                s_qk[0][h * QKS + c] = f2bf(fmaxf(tq, 0.1f * tq));
            }
        }
        // ---- front stage, point 1 (pg reused; same-wave WAR is in-order)
        {
            unsigned int u[H];
            #pragma unroll
            for (int h = 0; h < H; ++h)
                u[h] = *(const unsigned int*)&qkv[(size_t)s_idx[p1][h] * 768 + 256 + 2 * c];
            float qf = bf2f(qkv[(size_t)s_idx[p1][0] * 768 + c]);

            bf16x8 ga = *(bf16x8*)&s_d1[1][col * D1S + quad * 8];
            bf16x8 gb = *(bf16x8*)&s_d1[1][col * D1S + 32 + quad * 8];
            #pragma unroll
            for (int t = 0; t < 4; ++t) {
                f32x4 acc = {0.f, 0.f, 0.f, 0.f};
                acc = __builtin_amdgcn_mfma_f32_16x16x32_bf16(ga, wd2f[0][t], acc, 0, 0, 0);
                acc = __builtin_amdgcn_mfma_f32_16x16x32_bf16(gb, wd2f[1][t], acc, 0, 0, 0);
                #pragma unroll
                for (int rr = 0; rr < 4; ++rr)
                    pg[(quad * 4 + rr) * PGS + t * 16 + col] = acc[rr];
            }
            #pragma unroll
            for (int h = 0; h < H; ++h) {
                float g = pg[h * PGS + lane] + b2;
                float nk = __uint_as_float(u[h] << 16);
                float nv = __uint_as_float(u[h] & 0xffff0000u);
                vg1[h] = nv - g;
                float tq = qf - nk - g;
                s_qk[1][h * QKS + c] = f2bf(fmaxf(tq, 0.1f * tq));
            }
        }
        __syncthreads();                                    // bar 2

        // ---- a1 = lrelu(qk @ Wa1 + ba1): ALL waves (pair-split by pw)
        {
            f32x4 acc = {0.f, 0.f, 0.f, 0.f};
            #pragma unroll
            for (int kt = 0; kt < 8; ++kt) {
                bf16x8 a = *(bf16x8*)&s_qk[pw][col * QKS + kt * 32 + quad * 8];
                acc = __builtin_amdgcn_mfma_f32_16x16x32_bf16(a, wa1f[kt], acc, 0, 0, 0);
            }
            int j = hx * 16 + col;
            float bb = ba1[j];
            #pragma unroll
            for (int rr = 0; rr < 4; ++rr) {
                float v = acc[rr] + bb;
                s_a1[pw][(quad * 4 + rr) * A1S + j] = f2bf(fmaxf(v, 0.1f * v));
            }
        }
        __syncthreads();                                    // bar 3

        // ---- a2 = a1 @ Wa2 + ba2: ALL waves
        {
            bf16x8 aa = *(bf16x8*)&s_a1[pw][col * A1S + quad * 8];
            f32x4 acc = {0.f, 0.f, 0.f, 0.f};
            acc = __builtin_amdgcn_mfma_f32_16x16x32_bf16(aa, wa2f, acc, 0, 0, 0);
            int j = hx * 16 + col;
            float bb = ba2[j];
            #pragma unroll
            for (int rr = 0; rr < 4; ++rr)
                s_a2[pw][(quad * 4 + rr) * A2S + j] = acc[rr] + bb;
        }
        __syncthreads();                                    // bar 4

        // ---- softmax over h: wave 0 -> p0 buffer, wave 1 -> p1 buffer
        if (wave < 2) {
            float* a2b = s_a2[wave];
            int j = lane & 31, hb = (lane >> 5) * 8;
            float vals[8];
            float mx = -1e30f;
            #pragma unroll
            for (int i = 0; i < 8; ++i) {
                vals[i] = a2b[(hb + i) * A2S + j];
                mx = fmaxf(mx, vals[i]);
            }
            mx = fmaxf(mx, __shfl_xor(mx, 32));
            float sum = 0.f;
            #pragma unroll
            for (int i = 0; i < 8; ++i) { vals[i] = __expf(vals[i] - mx); sum += vals[i]; }
            sum += __shfl_xor(sum, 32);
            float inv = 1.f / sum;
            #pragma unroll
            for (int i = 0; i < 8; ++i) a2b[(hb + i) * A2S + j] = vals[i] * inv;
        }
        __syncthreads();                                    // bar 5

        // ---- out for both points
        float o0 = 0.f, o1 = 0.f;
        const int aj = c >> 3;
        #pragma unroll
        for (int h = 0; h < H; ++h) {
            o0 += vg0[h] * s_a2[0][h * A2S + aj];
            o1 += vg1[h] * s_a2[1][h * A2S + aj];
        }
        out[(size_t)(n0 + p0) * C + c] = o0;
        out[(size_t)(n0 + p1) * C + c] = o1;
    }
}

// ---------------------------------------------------------------------------

extern "C" void kernel_launch(void* const* d_in, const int* in_sizes, int n_in,
                              void* d_out, int out_size, void* d_ws, size_t ws_size,
                              hipStream_t stream) {
    const float* q_pts   = (const float*)d_in[0];
    const float* s_pts   = (const float*)d_in[1];
    const float* s_feats = (const float*)d_in[2];
    const int*   nbr     = (const int*)d_in[3];
    const float* Wq  = (const float*)d_in[4];
    const float* bq  = (const float*)d_in[5];
    const float* Wk  = (const float*)d_in[6];
    const float* bk  = (const float*)d_in[7];
    const float* Wv  = (const float*)d_in[8];
    const float* bv  = (const float*)d_in[9];
    const float* Wd1 = (const float*)d_in[10];
    const float* bd1 = (const float*)d_in[11];
    const float* Wd2 = (const float*)d_in[12];
    const float* bd2 = (const float*)d_in[13];
    const float* Wa1 = (const float*)d_in[14];
    const float* ba1 = (const float*)d_in[15];
    const float* Wa2 = (const float*)d_in[16];
    const float* ba2 = (const float*)d_in[17];

    float* out = (float*)d_out;
    char* ws = (char*)d_ws;
    unsigned short* A_bf16    = (unsigned short*)(ws);                 // 25.6 MB
    unsigned short* qkvb      = (unsigned short*)(ws + 25600000);      // 76.8 MB
    unsigned short* attnFrags = (unsigned short*)(ws + 102400000);     // 51.2 KB
    unsigned short* gemmFrags = (unsigned short*)(ws + 102451200);     // 384 KB

    prep_all<<<6359, 256, 0, stream>>>(s_feats, Wq, Wk, Wv, Wd2, Wa1, Wa2,
                                       A_bf16, gemmFrags, attnFrags);

    dim3 g1(6, (N_PTS + 127) / 128);
    qkv_gemm_mfma<<<g1, 256, 0, stream>>>(A_bf16, gemmFrags, bq, bk, bv, qkvb);

    attn_mfma<<<(N_PTS / PPB), 256, 0, stream>>>(qkvb, q_pts, s_pts, nbr,
                                                 Wd1, bd1, bd2, attnFrags,
                                                 ba1, ba2, out);
}

// Round 7
// 402.317 us; speedup vs baseline: 1.0428x; 1.0428x over previous
//
#include <hip/hip_runtime.h>
#include <cstdint>
#include <cstddef>

#define N_PTS 50000
#define H 16
#define CIN 256
#define C 256
#define CPG 32
#define CR 64

typedef short bf16x8 __attribute__((ext_vector_type(8)));
typedef float f32x4 __attribute__((ext_vector_type(4)));

// Native bf16 convert: compiler lowers fptrunc -> v_cvt_pk_bf16_f32 (1 VALU op
// vs ~4 for the manual bit-twiddle; same round-to-nearest-even semantics).
__device__ __forceinline__ unsigned short f2bf(float f) {
    __bf16 b = (__bf16)f;
    return __builtin_bit_cast(unsigned short, b);
}
__device__ __forceinline__ float bf2f(unsigned short s) {
    return __uint_as_float(((unsigned int)s) << 16);
}

// ---------------------------------------------------------------------------
// Merged prep: [0,6250) convert s_feats->bf16; [6250,6346) pack Wq|Wk|Wv
// B-frags; [6346,6359) pack Wd2/Wa1/Wa2 B-frags.
//   frag(kt,nt): lane l holds B[kt*32+(l>>4)*8+j][nt*16+(l&15)], j=0..7
// ---------------------------------------------------------------------------
__global__ __launch_bounds__(256) void prep_all(
    const float* __restrict__ feats,
    const float* __restrict__ Wq, const float* __restrict__ Wk,
    const float* __restrict__ Wv,
    const float* __restrict__ Wd2, const float* __restrict__ Wa1,
    const float* __restrict__ Wa2,
    unsigned short* __restrict__ A_bf16,
    unsigned short* __restrict__ gemmFrags,
    unsigned short* __restrict__ attnFrags)
{
    int bid = blockIdx.x;
    if (bid < 6250) {
        size_t i = ((size_t)bid * 256 + threadIdx.x) * 8;
        float4 f0 = *(const float4*)&feats[i];
        float4 f1 = *(const float4*)&feats[i + 4];
        unsigned short t[8] = {f2bf(f0.x), f2bf(f0.y), f2bf(f0.z), f2bf(f0.w),
                               f2bf(f1.x), f2bf(f1.y), f2bf(f1.z), f2bf(f1.w)};
        *(bf16x8*)&A_bf16[i] = *(bf16x8*)t;
    } else if (bid < 6346) {
        int t = (bid - 6250) * 256 + threadIdx.x;   // 0..24575
        int lane = t & 63;
        int f = t >> 6;                              // kt*48 + ntg
        int ntg = f % 48;
        const float* W = ntg < 16 ? Wq : (ntg < 32 ? Wk : Wv);
        int colc = (ntg & 15) * 16 + (lane & 15);
        int row0 = (f / 48) * 32 + ((lane >> 4) << 3);
        unsigned short tmp[8];
        #pragma unroll
        for (int j = 0; j < 8; ++j) tmp[j] = f2bf(W[(size_t)(row0 + j) * 256 + colc]);
        *(bf16x8*)&gemmFrags[(size_t)t * 8] = *(bf16x8*)tmp;
    } else {
        int t = (bid - 6346) * 256 + threadIdx.x;
        if (t >= 3200) return;
        const float* W; int Nc, NT, loc, base;
        if (t < 2048)      { W = Wd2; Nc = 256; NT = 16; loc = t;        base = 0; }
        else if (t < 3072) { W = Wa1; Nc = 32;  NT = 2;  loc = t - 2048; base = 16384; }
        else               { W = Wa2; Nc = 32;  NT = 2;  loc = t - 3072; base = 24576; }
        int f = loc >> 6, lane = loc & 63;
        int kt = f / NT, nt = f - kt * NT;
        int colc = nt * 16 + (lane & 15);
        int row0 = kt * 32 + ((lane >> 4) << 3);
        unsigned short tmp[8];
        #pragma unroll
        for (int j = 0; j < 8; ++j) tmp[j] = f2bf(W[(size_t)(row0 + j) * Nc + colc]);
        *(bf16x8*)&attnFrags[(size_t)(base + loc * 8)] = *(bf16x8*)tmp;
    }
}

// ---------------------------------------------------------------------------
// QKV GEMM v3: B-tile staged in LDS (the round-6 change).
// Theory: r1 (LDS-A, barrier-heavy) and r2 (direct-A, barrier-free) timed
// identically because BOTH loaded B-frags from global (L2, ~200cy) inside the
// MFMA inner loop -- the latency chain neither structure broke. v3 stages the
// block's full 64KB B-tile (bx slice) into LDS once, coalesced; inner loop
// reads B via ds_read_b128 (contiguous 1KB/frag, conflict-free).
// A stays direct-global (L3-resident; verified r2).
// kv interleaved output: row = [0..255]=q, [256+2c]=k[c], [257+2c]=v[c].
// ---------------------------------------------------------------------------
__global__ __launch_bounds__(256) void qkv_gemm_mfma(
    const unsigned short* __restrict__ A,       // [N][256] bf16
    const unsigned short* __restrict__ wfrags,
    const float* __restrict__ bq, const float* __restrict__ bk,
    const float* __restrict__ bv, unsigned short* __restrict__ out)
{
    __shared__ unsigned short s_b[64 * 64 * 8];   // 8kt x 8nt x 64lane x 8 = 64KB
    const int tid = threadIdx.x;
    const int lane = tid & 63, wave = tid >> 6;
    const int quad = lane >> 4, col16 = lane & 15;
    const int bx = blockIdx.x, by = blockIdx.y;

    // ---- stage B-tile: 4096 x 16B chunks, 16 per thread, coalesced.
    // chunk ci: frag f = ci>>6 (kt=f>>3, nt=f&7), within-frag w = ci&63.
    // src frag(kt,nt) = wfrags[((kt*48 + bx*8 + nt)*64 + w)*8]; dst = ci*8.
    #pragma unroll
    for (int i = 0; i < 16; ++i) {
        int ci = i * 256 + tid;
        int f = ci >> 6, w = ci & 63;
        int kt = f >> 3, nt = f & 7;
        *(bf16x8*)&s_b[(size_t)ci * 8] =
            *(const bf16x8*)&wfrags[((size_t)(kt * 48 + bx * 8 + nt) * 64 + w) * 8];
    }

    int r0 = by * 128 + wave * 32 + col16;
    int r1 = r0 + 16;
    r0 = r0 < N_PTS ? r0 : N_PTS - 1;
    r1 = r1 < N_PTS ? r1 : N_PTS - 1;
    const unsigned short* a0p = &A[(size_t)r0 * 256 + quad * 8];
    const unsigned short* a1p = &A[(size_t)r1 * 256 + quad * 8];

    f32x4 acc[2][8] = {};
    __syncthreads();

    #pragma unroll 2
    for (int kt = 0; kt < 8; ++kt) {
        bf16x8 af0 = *(const bf16x8*)(a0p + kt * 32);
        bf16x8 af1 = *(const bf16x8*)(a1p + kt * 32);
        #pragma unroll
        for (int nt = 0; nt < 8; ++nt) {
            bf16x8 bf = *(bf16x8*)&s_b[((kt * 8 + nt) * 64 + lane) * 8];
            acc[0][nt] = __builtin_amdgcn_mfma_f32_16x16x32_bf16(af0, bf, acc[0][nt], 0, 0, 0);
            acc[1][nt] = __builtin_amdgcn_mfma_f32_16x16x32_bf16(af1, bf, acc[1][nt], 0, 0, 0);
        }
    }

    const int mode = bx >> 1;   // 0=q 1=k 2=v
    const float* bias = mode == 0 ? bq : (mode == 1 ? bk : bv);
    #pragma unroll
    for (int nt = 0; nt < 8; ++nt) {
        int cIn = (bx & 1) * 128 + nt * 16 + col16;
        float bb = bias[cIn];
        int pos = mode == 0 ? cIn : (256 + 2 * cIn + (mode == 2 ? 1 : 0));
        #pragma unroll
        for (int mt = 0; mt < 2; ++mt) {
            #pragma unroll
            for (int r = 0; r < 4; ++r) {
                int row = by * 128 + wave * 32 + mt * 16 + quad * 4 + r;
                if (row < N_PTS)
                    out[(size_t)row * 768 + pos] = f2bf(acc[mt][nt][r] + bb);
            }
        }
    }
}

// ---------------------------------------------------------------------------
// Fused attention v3 structure (round-5 verified 213.3 us), only change this
// round: f2bf is now the native single-instruction convert (affects qk/d1/a1
// stores: ~16 converts/point/thread -> ~10% VALU cut predicted).
// Occupancy axis abandoned: hints (r4), no-hint (r5), pair-restructure (r6)
// all netted <=0; residency pinned ~3 blocks/CU.
// ---------------------------------------------------------------------------
#define D1S 72
#define PGS 66      // private geom row stride (dwords): 2-way banks on rd & wr
#define QKS 264
#define A1S 40
#define A2S 33

__global__ __launch_bounds__(256) void attn_mfma(
    const unsigned short* __restrict__ qkv,     // [N][768] q | kv-interleaved
    const float* __restrict__ q_pts, const float* __restrict__ s_pts,
    const int* __restrict__ nbr,
    const float* __restrict__ Wd1, const float* __restrict__ bd1,
    const float* __restrict__ bd2,
    const unsigned short* __restrict__ frags,
    const float* __restrict__ ba1, const float* __restrict__ ba2,
    float* __restrict__ out)
{
    __shared__ unsigned short s_d1[H * D1S];
    __shared__ float          s_pg[4 * H * PGS];   // wave-private geom tiles
    __shared__ unsigned short s_qk[H * QKS];
    __shared__ unsigned short s_a1[H * A1S];
    __shared__ float          s_a2[H * A2S];
    __shared__ float          s_rel[4][H][3];
    __shared__ int            s_idx[4][H];

    const int tid = threadIdx.x;
    const int lane = tid & 63, wave = tid >> 6;
    const int quad = lane >> 4, col = lane & 15;
    const int n0 = blockIdx.x * 4;
    const int c = tid;                 // == wave*64 + lane

    if (tid < 64) {
        int pp = tid >> 4, hh = tid & 15;
        int idx = nbr[(size_t)(n0 + pp) * H + hh];
        s_idx[pp][hh] = idx;
        #pragma unroll
        for (int x = 0; x < 3; ++x)
            s_rel[pp][hh][x] = s_pts[(size_t)idx * 3 + x] - q_pts[(size_t)(n0 + pp) * 3 + x];
    }

    const float w1x = Wd1[lane], w1y = Wd1[64 + lane], w1z = Wd1[128 + lane];
    const float b1 = bd1[lane];
    const float b2 = bd2[c];
    bf16x8 wd2f[2][4];
    #pragma unroll
    for (int t = 0; t < 4; ++t) {
        wd2f[0][t] = *(const bf16x8*)&frags[((size_t)((0 * 16 + wave * 4 + t) * 64 + lane)) * 8];
        wd2f[1][t] = *(const bf16x8*)&frags[((size_t)((1 * 16 + wave * 4 + t) * 64 + lane)) * 8];
    }
    bf16x8 wa1f[8];
    bf16x8 wa2f = {0,0,0,0,0,0,0,0};
    if (wave < 2) {
        #pragma unroll
        for (int kt = 0; kt < 8; ++kt)
            wa1f[kt] = *(const bf16x8*)&frags[16384 + ((size_t)((kt * 2 + wave) * 64 + lane)) * 8];
        wa2f = *(const bf16x8*)&frags[24576 + ((size_t)(wave * 64 + lane)) * 8];
    }
    __syncthreads();

    float* pg = &s_pg[wave * (H * PGS)];

    for (int p = 0; p < 4; ++p) {
        const int n = n0 + p;

        // d1 = lrelu(rel @ Wd1 + bd1)  (cross-wave, needs the barrier below)
        #pragma unroll
        for (int pass = 0; pass < 4; ++pass) {
            int h = pass * 4 + wave;
            float v = b1 + s_rel[p][h][0] * w1x + s_rel[p][h][1] * w1y + s_rel[p][h][2] * w1z;
            s_d1[h * D1S + lane] = f2bf(fmaxf(v, 0.1f * v));
        }
        __syncthreads();

        // ---- issue all gathers now; no barrier until after they're consumed
        unsigned int u[H];
        #pragma unroll
        for (int h = 0; h < H; ++h)
            u[h] = *(const unsigned int*)&qkv[(size_t)s_idx[p][h] * 768 + 256 + 2 * c];
        float qf = bf2f(qkv[(size_t)s_idx[p][0] * 768 + c]);

        // geom = d1 @ Wd2 (16x64 @ 64x256) -> wave-private C-tile in LDS
        {
            bf16x8 ga = *(bf16x8*)&s_d1[col * D1S + quad * 8];
            bf16x8 gb = *(bf16x8*)&s_d1[col * D1S + 32 + quad * 8];
            #pragma unroll
            for (int t = 0; t < 4; ++t) {
                f32x4 acc = {0.f, 0.f, 0.f, 0.f};
                acc = __builtin_amdgcn_mfma_f32_16x16x32_bf16(ga, wd2f[0][t], acc, 0, 0, 0);
                acc = __builtin_amdgcn_mfma_f32_16x16x32_bf16(gb, wd2f[1][t], acc, 0, 0, 0);
                #pragma unroll
                for (int rr = 0; rr < 4; ++rr)
                    pg[(quad * 4 + rr) * PGS + t * 16 + col] = acc[rr];
            }
        }
        // same-wave ds_write -> ds_read: lgkmcnt only, NO __syncthreads here.

        // elementwise: consume gathered kv + private geom; build vg + qk
        float vg[H];
        #pragma unroll
        for (int h = 0; h < H; ++h) {
            float g = pg[h * PGS + lane] + b2;
            float nk = __uint_as_float(u[h] << 16);
            float nv = __uint_as_float(u[h] & 0xffff0000u);
            vg[h] = nv - g;
            float tq = qf - nk - g;
            s_qk[h * QKS + c] = f2bf(fmaxf(tq, 0.1f * tq));
        }
        __syncthreads();

        // a1 = lrelu(qk @ Wa1 + ba1) on waves 0,1
        if (wave < 2) {
            f32x4 acc = {0.f, 0.f, 0.f, 0.f};
            #pragma unroll
            for (int kt = 0; kt < 8; ++kt) {
                bf16x8 a = *(bf16x8*)&s_qk[col * QKS + kt * 32 + quad * 8];
                acc = __builtin_amdgcn_mfma_f32_16x16x32_bf16(a, wa1f[kt], acc, 0, 0, 0);
            }
            int j = wave * 16 + col;
            float bb = ba1[j];
            #pragma unroll
            for (int rr = 0; rr < 4; ++rr) {
                float v = acc[rr] + bb;
                s_a1[(quad * 4 + rr) * A1S + j] = f2bf(fmaxf(v, 0.1f * v));
            }
        }
        __syncthreads();

        // a2 = a1 @ Wa2 + ba2 on waves 0,1
        if (wave < 2) {
            bf16x8 aa = *(bf16x8*)&s_a1[col * A1S + quad * 8];
            f32x4 acc = {0.f, 0.f, 0.f, 0.f};
            acc = __builtin_amdgcn_mfma_f32_16x16x32_bf16(aa, wa2f, acc, 0, 0, 0);
            int j = wave * 16 + col;
            float bb = ba2[j];
            #pragma unroll
            for (int rr = 0; rr < 4; ++rr)
                s_a2[(quad * 4 + rr) * A2S + j] = acc[rr] + bb;
        }
        __syncthreads();

        // softmax over h, wave 0
        if (wave == 0) {
            int j = lane & 31, hb = (lane >> 5) * 8;
            float vals[8];
            float mx = -1e30f;
            #pragma unroll
            for (int i = 0; i < 8; ++i) {
                vals[i] = s_a2[(hb + i) * A2S + j];
                mx = fmaxf(mx, vals[i]);
            }
            mx = fmaxf(mx, __shfl_xor(mx, 32));
            float sum = 0.f;
            #pragma unroll
            for (int i = 0; i < 8; ++i) { vals[i] = __expf(vals[i] - mx); sum += vals[i]; }
            sum += __shfl_xor(sum, 32);
            float inv = 1.f / sum;
            #pragma unroll
            for (int i = 0; i < 8; ++i) s_a2[(hb + i) * A2S + j] = vals[i] * inv;
        }
        __syncthreads();

        // out[n][c] = sum_h vg[h] * attn[h][c>>3]
        float o = 0.f;
        const int aj = c >> 3;
        #pragma unroll
        for (int h = 0; h < H; ++h) o += vg[h] * s_a2[h * A2S + aj];
        out[(size_t)n * C + c] = o;
    }
}

// ---------------------------------------------------------------------------

extern "C" void kernel_launch(void* const* d_in, const int* in_sizes, int n_in,
                              void* d_out, int out_size, void* d_ws, size_t ws_size,
                              hipStream_t stream) {
    const float* q_pts   = (const float*)d_in[0];
    const float* s_pts   = (const float*)d_in[1];
    const float* s_feats = (const float*)d_in[2];
    const int*   nbr     = (const int*)d_in[3];
    const float* Wq  = (const float*)d_in[4];
    const float* bq  = (const float*)d_in[5];
    const float* Wk  = (const float*)d_in[6];
    const float* bk  = (const float*)d_in[7];
    const float* Wv  = (const float*)d_in[8];
    const float* bv  = (const float*)d_in[9];
    const float* Wd1 = (const float*)d_in[10];
    const float* bd1 = (const float*)d_in[11];
    const float* Wd2 = (const float*)d_in[12];
    const float* bd2 = (const float*)d_in[13];
    const float* Wa1 = (const float*)d_in[14];
    const float* ba1 = (const float*)d_in[15];
    const float* Wa2 = (const float*)d_in[16];
    const float* ba2 = (const float*)d_in[17];

    float* out = (float*)d_out;
    char* ws = (char*)d_ws;
    unsigned short* A_bf16    = (unsigned short*)(ws);                 // 25.6 MB
    unsigned short* qkvb      = (unsigned short*)(ws + 25600000);      // 76.8 MB
    unsigned short* attnFrags = (unsigned short*)(ws + 102400000);     // 51.2 KB
    unsigned short* gemmFrags = (unsigned short*)(ws + 102451200);     // 384 KB

    prep_all<<<6359, 256, 0, stream>>>(s_feats, Wq, Wk, Wv, Wd2, Wa1, Wa2,
                                       A_bf16, gemmFrags, attnFrags);

    dim3 g1(6, (N_PTS + 127) / 128);
    qkv_gemm_mfma<<<g1, 256, 0, stream>>>(A_bf16, gemmFrags, bq, bk, bv, qkvb);

    attn_mfma<<<(N_PTS / 4), 256, 0, stream>>>(qkvb, q_pts, s_pts, nbr,
                                               Wd1, bd1, bd2, attnFrags,
                                               ba1, ba2, out);
}